// Round 6
// baseline (456.313 us; speedup 1.0000x reference)
//
#include <hip/hip_runtime.h>

// ---------------------------------------------------------------------------
// STN pipeline, theta chain in FP64 (must match np float64 reference: sampler
// has floor() discontinuities at coord==223 with O(100..1000) jumps; f32
// noise upstream of theta flips floors -> fails. Any-order f64 lands ~1e-13
// from the np value -> flip set identical -> absmax small & stable).
//
// R14: conv1 PERSISTENT blocks + LDS double-buffer. Model revision: one wave
// of back-to-back f64 FMA saturates a SIMD (4-cyc issue each), so occupancy
// was never the lever — the 27% VALU-idle is per-block staging+barrier
// exposure at ~1 resident block/CU. 1792 tiles = 256 blocks x 7 tiles:
// per tile {issue next tile's global loads to regs; compute cur buf
// (bit-identical R10 inner loop); write regs -> other buf; barrier}.
// LDS 2x41KB padded >80KB forces exactly 1 block/CU (no packing pathology).
// R13: parity-planar LDS FAILED (write-scatter conflicts 1.67M, 211us).
// R12: tall tile FAILED (193us). R11: conv2 scalar weights (neutral).
// R10: conv1 scalar weights 181->164us.
// ---------------------------------------------------------------------------

// Convert conv1 w+b and conv2 w+b to f64 once per graph execution.
// wd layout: [0,1176) conv1_w | [1176,1184) conv1_b
//            [1184,3184) conv2_w (native (ky,kx,c,oc) order) | [3184,3194) conv2_b
__global__ __launch_bounds__(256) void k_wcvt(
    const float* __restrict__ w1, const float* __restrict__ b1,
    const float* __restrict__ w2, const float* __restrict__ b2,
    double* __restrict__ wd) {
  int t = blockIdx.x * 256 + threadIdx.x;
  if (t < 1176) wd[t] = (double)w1[t];
  else if (t < 1184) wd[t] = (double)b1[t - 1176];
  else if (t < 3184) wd[t] = (double)w2[t - 1184];
  else if (t < 3194) wd[t] = (double)b2[t - 3184];
}

// conv1 + relu + maxpool : in (64,224,224,3) f32 -> out (64,109,109,8) f64
// Persistent: 256 blocks x 7 tiles each; tile = 4 pooled rows x 109 px
// (436 work items on 448 threads). Double-buffered 14-row band.
// Buffer stride 10260 floats (row stride 672; pad keeps total >80KB and
// win[1] 16B-aligned). Weights via scalar loads from global f64 wd.
__global__ __launch_bounds__(448) void k_conv1(
    const float* __restrict__ in, const double* __restrict__ wd,
    double* __restrict__ out) {
  __shared__ float win[2][10260];   // 2 x (14*672=9408 used) = 82080 B total

  int t = threadIdx.x;
  int px = t % 109;
  int wrow = t / 109;               // 0..4 (compute uses <4)
  int lrb = 2 * wrow;

  float4 st[6];                     // staged next-tile band (6 rounds x f4)
  int gt0 = blockIdx.x * 7;         // 7 consecutive global tiles per block

  // load tile gt's 14-row band (row clamped to 223) into regs
  auto load_tile = [&](int gt) {
    int b = gt / 28, tl = gt % 28;
    int r0 = 8 * tl;
    const float* ibb = in + (size_t)b * 150528;
#pragma unroll
    for (int r = 0; r < 6; ++r) {
      int idx = t + r * 448;
      if (idx < 2352) {             // 14 rows * 168 float4
        int rr = idx / 168, c4 = idx % 168;
        int row = min(r0 + rr, 223);
        st[r] = reinterpret_cast<const float4*>(ibb + (size_t)row * 672)[c4];
      }
    }
  };
  auto write_tile = [&](int buf) {
#pragma unroll
    for (int r = 0; r < 6; ++r) {
      int idx = t + r * 448;
      if (idx < 2352)
        reinterpret_cast<float4*>(&win[buf][0])[idx] = st[r];
    }
  };

  load_tile(gt0);
  write_tile(0);
  __syncthreads();

  for (int j = 0; j < 7; ++j) {
    int gt = gt0 + j;
    int b = gt / 28, tl = gt % 28;
    int py0 = 4 * tl;
    int cur = j & 1;

    if (j < 6) load_tile(gt + 1);   // issue early; lands under compute

    int py = py0 + wrow;
    if (t < 436 && py < 109) {
      const float* wbuf = &win[cur][0];

      double acc[2][2][8];
#pragma unroll
      for (int ii = 0; ii < 2; ++ii)
#pragma unroll
        for (int jj = 0; jj < 2; ++jj)
#pragma unroll
          for (int k = 0; k < 8; ++k) acc[ii][jj][k] = 0.0;

      for (int ky = 0; ky < 7; ++ky) {
        const float* r0p = &wbuf[(lrb + ky) * 672 + 6 * px];
        const float* r1p = r0p + 672;
        float a0[24], a1[24];
#pragma unroll
        for (int jj = 0; jj < 12; ++jj) {
          float2 u = reinterpret_cast<const float2*>(r0p)[jj];
          a0[2 * jj] = u.x; a0[2 * jj + 1] = u.y;
          float2 v = reinterpret_cast<const float2*>(r1p)[jj];
          a1[2 * jj] = v.x; a1[2 * jj + 1] = v.y;
        }
        const double* wk = wd + ky * 168;   // 7 kx * 3 c * 8 oc per ky
#pragma unroll
        for (int kx = 0; kx < 7; ++kx) {
#pragma unroll
          for (int c = 0; c < 3; ++c) {
            double v00 = (double)a0[kx * 3 + c];
            double v01 = (double)a0[kx * 3 + 3 + c];
            double v10 = (double)a1[kx * 3 + c];
            double v11 = (double)a1[kx * 3 + 3 + c];
            const double* wp = wk + (kx * 3 + c) * 8;  // wave-uniform -> s_load
#pragma unroll
            for (int oc = 0; oc < 8; ++oc) {
              double wv = wp[oc];
              acc[0][0][oc] = fma(v00, wv, acc[0][0][oc]);
              acc[0][1][oc] = fma(v01, wv, acc[0][1][oc]);
              acc[1][0][oc] = fma(v10, wv, acc[1][0][oc]);
              acc[1][1][oc] = fma(v11, wv, acc[1][1][oc]);
            }
          }
        }
      }

      double* op = out + ((size_t)b * 11881 + (size_t)py * 109 + px) * 8;
#pragma unroll
      for (int oc = 0; oc < 8; ++oc) {
        double m = fmax(fmax(acc[0][0][oc], acc[0][1][oc]),
                        fmax(acc[1][0][oc], acc[1][1][oc]));
        op[oc] = fmax(m + wd[1176 + oc], 0.0);
      }
    }

    if (j < 6) write_tile(cur ^ 1);   // other buffer; cur's readers not touched
    __syncthreads();                  // publish before next tile's compute
  }
}

// conv2 + relu + maxpool : in (64,109,109,8) f64 -> out (64,52,52,10) f64
// Block 512 = 2 oc-halves (wave-uniform, t>>8) x 256 (208 px-positions used).
// Parity-split planar band win2[cc][rr][par][56]; two channel-half passes.
// wd2: f64 conv2 weights, native ((ky*5+kx)*8+c)*10+oc layout; bias at 2000.
__global__ __launch_bounds__(512) void k_conv2(
    const double* __restrict__ in, const double* __restrict__ wd2,
    double* __restrict__ out) {
  __shared__ double win2[4 * 12 * 2 * 56];  // [cc][rr][par][k] = 43008 B

  // XCD swizzle: 13 tiles/batch (52/4 exact), 8 batches/group.
  int g = blockIdx.x & 7;
  int i = blockIdx.x >> 3;          // 0..103
  int b = g * 8 + i / 13;
  int tile = i % 13;
  int py0 = 4 * tile;
  int r0 = 8 * tile;                // 12-row band, max row 107 <= 108

  int t = threadIdx.x;
  // oh is uniform within each 64-lane wave (waves 0-3 -> 0, waves 4-7 -> 1);
  // readfirstlane forces the compiler to treat it as scalar so the weight
  // address computes in SGPRs -> s_load.
  int oh = __builtin_amdgcn_readfirstlane(t >> 8);
  int p = t & 255;                  // 0..255; 208 used
  bool valid = p < 208;
  int px = p % 52;
  int lrb = 2 * (p / 52);           // 0,2,4,6

  const double* wb = wd2 + oh * 5;  // scalar base for this oc-half

  double acc[2][2][5];
#pragma unroll
  for (int ii = 0; ii < 2; ++ii)
#pragma unroll
    for (int jj = 0; jj < 2; ++jj)
#pragma unroll
      for (int k = 0; k < 5; ++k) acc[ii][jj][k] = 0.0;

  const double* ib = in + (size_t)b * 11881 * 8;

  for (int h = 0; h < 2; ++h) {
    __syncthreads();  // protects win2 reuse across passes
    // stage 12 rows x 109 x channels [h*4..h*4+3], parity-split on x
    for (int idx = threadIdx.x; idx < 12 * 109 * 2; idx += 512) {
      int d2 = idx & 1;               // channel pair (0-1 / 2-3)
      int x  = (idx >> 1) % 109;
      int rr = (idx >> 1) / 109;
      double2 v = *reinterpret_cast<const double2*>(
          ib + ((size_t)(r0 + rr) * 109 + x) * 8 + h * 4 + d2 * 2);
      int par = x & 1, k = x >> 1;
      win2[(((d2 * 2) * 12 + rr) * 2 + par) * 56 + k] = v.x;
      win2[(((d2 * 2 + 1) * 12 + rr) * 2 + par) * 56 + k] = v.y;
    }
    __syncthreads();

    if (valid) {
#pragma unroll
      for (int ky = 0; ky < 5; ++ky) {
        int rr0 = lrb + ky;
#pragma unroll
        for (int cc = 0; cc < 4; ++cc) {
          int c = h * 4 + cc;
          // hoist the 12 window doubles for this (ky,cc): rows rr0,rr0+1,
          // both parities, k = px..px+2.  x = 2px+j -> par=j&1, k=px+(j>>1).
          const double* pe0 = &win2[((cc * 12 + rr0) * 2 + 0) * 56 + px];
          const double* po0 = &win2[((cc * 12 + rr0) * 2 + 1) * 56 + px];
          const double* pe1 = pe0 + 112;   // rr0+1
          const double* po1 = po0 + 112;
          double e0[3] = {pe0[0], pe0[1], pe0[2]};
          double o0[3] = {po0[0], po0[1], po0[2]};
          double e1[3] = {pe1[0], pe1[1], pe1[2]};
          double o1[3] = {po1[0], po1[1], po1[2]};
#pragma unroll
          for (int kx = 0; kx < 5; ++kx) {
            double v00, v01, v10, v11;
            if (kx & 1) {
              v00 = o0[kx >> 1]; v01 = e0[(kx >> 1) + 1];
              v10 = o1[kx >> 1]; v11 = e1[(kx >> 1) + 1];
            } else {
              v00 = e0[kx >> 1]; v01 = o0[kx >> 1];
              v10 = e1[kx >> 1]; v11 = o1[kx >> 1];
            }
            const double* wp = wb + ((ky * 5 + kx) * 8 + c) * 10;  // scalar
#pragma unroll
            for (int oc = 0; oc < 5; ++oc) {
              double wv = wp[oc];
              acc[0][0][oc] = fma(v00, wv, acc[0][0][oc]);
              acc[0][1][oc] = fma(v01, wv, acc[0][1][oc]);
              acc[1][0][oc] = fma(v10, wv, acc[1][0][oc]);
              acc[1][1][oc] = fma(v11, wv, acc[1][1][oc]);
            }
          }
        }
      }
    }
  }

  if (valid) {
    int pix = py0 * 52 + p;           // p row-major within tile
    double* op = out + ((size_t)b * 2704 + pix) * 10 + oh * 5;
#pragma unroll
    for (int oc = 0; oc < 5; ++oc) {
      double m = fmax(fmax(acc[0][0][oc], acc[0][1][oc]),
                      fmax(acc[1][0][oc], acc[1][1][oc]));
      op[oc] = fmax(m + wd2[2000 + oh * 5 + oc], 0.0);
    }
  }
}

// fc1 partial dots: grid 1024 = (64 b) x (16 q); block 256 = 32 oc x 8 strips.
__global__ __launch_bounds__(256) void k_fc1(
    const double* __restrict__ xs, const float* __restrict__ w1,
    double* __restrict__ part) {
  int b = blockIdx.x >> 4;
  int q = blockIdx.x & 15;
  int oc = threadIdx.x & 31;
  int s = threadIdx.x >> 5;
  const double* xrow = xs + (size_t)b * 27040;

  int i0 = q * 1690 + s * 212;
  int i1 = min(i0 + 212, q * 1690 + 1690);
  double s0 = 0.0, s1 = 0.0;
  for (int i = i0; i + 1 < i1; i += 2) {
    s0 = fma(xrow[i],     (double)w1[(size_t)i * 32 + oc],       s0);
    s1 = fma(xrow[i + 1], (double)w1[(size_t)(i + 1) * 32 + oc], s1);
  }
  if ((i1 - i0) & 1)
    s0 = fma(xrow[i1 - 1], (double)w1[(size_t)(i1 - 1) * 32 + oc], s0);

  __shared__ double red[8][32];
  red[s][oc] = s0 + s1;
  __syncthreads();
  if (threadIdx.x < 32) {
    double v = 0.0;
#pragma unroll
    for (int k = 0; k < 8; ++k) v += red[k][threadIdx.x];
    part[((size_t)b * 16 + q) * 32 + threadIdx.x] = v;
  }
}

// fc1 reduce + ReLU + fc2 -> theta. 64 blocks x 64 threads.
__global__ __launch_bounds__(64) void k_fc2(
    const double* __restrict__ part, const float* __restrict__ b1,
    const float* __restrict__ w2, const float* __restrict__ b2,
    double* __restrict__ theta) {
  int b = blockIdx.x;
  __shared__ double h1[32];
  if (threadIdx.x < 32) {
    double v = (double)b1[threadIdx.x];
#pragma unroll
    for (int q = 0; q < 16; ++q)
      v += part[((size_t)b * 16 + q) * 32 + threadIdx.x];
    h1[threadIdx.x] = v > 0.0 ? v : 0.0;
  }
  __syncthreads();
  if (threadIdx.x < 6) {
    double v = (double)b2[threadIdx.x];
#pragma unroll
    for (int k = 0; k < 32; ++k) v += h1[k] * (double)w2[k * 6 + threadIdx.x];
    theta[b * 6 + threadIdx.x] = v;
  }
}

// affine grid + bilinear sampler, reference-exact (incl. extrapolation quirk).
__global__ __launch_bounds__(256) void k_sample(
    const float* __restrict__ img, const double* __restrict__ theta,
    float* __restrict__ out) {
  int idx = blockIdx.x * 256 + threadIdx.x;
  if (idx >= 64 * 224 * 224) return;
  int x = idx % 224;
  int t = idx / 224;
  int y = t % 224;
  int b = t / 224;

  const double* th = theta + b * 6;
  double t0 = th[0], t1 = th[1], t2 = th[2];
  double t3 = th[3], t4 = th[4], t5 = th[5];

  double xn = -1.0 + x * (2.0 / 223.0);
  double yn = -1.0 + y * (2.0 / 223.0);
  double xf = 0.5 * (t0 * xn + t1 * yn + t2 + 1.0) * 223.0;
  double yf = 0.5 * (t3 * xn + t4 * yn + t5 + 1.0) * 223.0;

  int x0 = (int)floor(xf);
  int y0 = (int)floor(yf);
  x0 = min(max(x0, 0), 223);
  y0 = min(max(y0, 0), 223);
  int x1 = min(x0 + 1, 223);
  int y1 = min(y0 + 1, 223);

  double x0f = (double)x0, x1f = (double)x1;
  double y0f = (double)y0, y1f = (double)y1;
  // weights from UNCLIPPED xf/yf — reference semantics (extrapolates)
  double wa = (x1f - xf) * (y1f - yf);
  double wb = (x1f - xf) * (yf - y0f);
  double wc = (xf - x0f) * (y1f - yf);
  double wd = (xf - x0f) * (yf - y0f);

  const float* p = img + (size_t)b * 150528;
  const float* Ia = p + ((size_t)y0 * 224 + x0) * 3;
  const float* Ib = p + ((size_t)y1 * 224 + x0) * 3;
  const float* Ic = p + ((size_t)y0 * 224 + x1) * 3;
  const float* Id = p + ((size_t)y1 * 224 + x1) * 3;

  float* op = out + (size_t)idx * 3;
#pragma unroll
  for (int c = 0; c < 3; ++c) {
    op[c] = (float)(wa * (double)Ia[c] + wb * (double)Ib[c] +
                    wc * (double)Ic[c] + wd * (double)Id[c]);
  }
}

extern "C" void kernel_launch(void* const* d_in, const int* in_sizes, int n_in,
                              void* d_out, int out_size, void* d_ws, size_t ws_size,
                              hipStream_t stream) {
  const float* inputs  = (const float*)d_in[0];  // (64,224,224,3)
  const float* conv1_w = (const float*)d_in[1];  // (7,7,3,8)
  const float* conv1_b = (const float*)d_in[2];  // (8)
  const float* conv2_w = (const float*)d_in[3];  // (5,5,8,10)
  const float* conv2_b = (const float*)d_in[4];  // (10)
  const float* fc1_w   = (const float*)d_in[5];  // (27040,32)
  const float* fc1_b   = (const float*)d_in[6];  // (32)
  const float* fc2_w   = (const float*)d_in[7];  // (32,6)
  const float* fc2_b   = (const float*)d_in[8];  // (6)
  float* outp = (float*)d_out;                   // (64,224,224,3)

  // ws layout (16B aligned): theta | fc partials | f64 weights | pools
  double* theta = (double*)d_ws;                            // 384 dbl
  double* part  = (double*)((char*)d_ws + 4096);            // 32768 dbl
  double* wd    = (double*)((char*)d_ws + 4096 + 262144);   // 3194 dbl -> pad 3200 (25600B)
  double* pool1 = (double*)((char*)d_ws + 4096 + 262144 + 25600); // 6,083,072 d
  double* pool2 = pool1 + 6083072;                          // 1,730,560 d

  // Stage 0: f64 weight conversion (conv1 + conv2) for scalar-load path
  k_wcvt<<<13, 256, 0, stream>>>(conv1_w, conv1_b, conv2_w, conv2_b, wd);
  // Stage 1: persistent — 256 blocks x 7 tiles (1792 tiles exactly)
  k_conv1<<<256, 448, 0, stream>>>(inputs, wd, pool1);
  // Stage 2: 13 tiles/batch * 64 batches (512-thread blocks), XCD-grouped
  k_conv2<<<13 * 64, 512, 0, stream>>>(pool1, wd + 1184, pool2);
  // Stage 3
  k_fc1<<<1024, 256, 0, stream>>>(pool2, fc1_w, part);
  k_fc2<<<64, 64, 0, stream>>>(part, fc1_b, fc2_w, fc2_b, theta);
  // Stage 4
  k_sample<<<(64 * 224 * 224 + 255) / 256, 256, 0, stream>>>(inputs, theta, outp);
}

// Round 7
// 430.757 us; speedup vs baseline: 1.0593x; 1.0593x over previous
//
#include <hip/hip_runtime.h>

// ---------------------------------------------------------------------------
// STN pipeline, theta chain in FP64 (must match np float64 reference: sampler
// has floor() discontinuities at coord==223 with O(100..1000) jumps; f32
// noise upstream of theta flips floors -> fails. Any-order f64 lands ~1e-13
// from the np value -> flip set identical -> absmax small & stable).
//
// R15: ATTRIBUTION ROUND. conv1 reverted to the proven R10 structure
// (164us; R12 tall-tile 193, R13 parity-LDS 211, R14 persistent 215 all
// REFUTED restructures) and split into TWO half-batch launches (b0=0/32,
// bit-identical per-output math). Each half ~83us < everything that
// matters -> the true #2 kernel (conv2? fc1? sample?) surfaces in the
// rocprof top-5, ending the ~230us attribution blackout.
// R11: conv2 scalar weights (neutral). R10: conv1 scalar weights 181->164.
// ---------------------------------------------------------------------------

// Convert conv1 w+b and conv2 w+b to f64 once per graph execution.
// wd layout: [0,1176) conv1_w | [1176,1184) conv1_b
//            [1184,3184) conv2_w (native (ky,kx,c,oc) order) | [3184,3194) conv2_b
__global__ __launch_bounds__(256) void k_wcvt(
    const float* __restrict__ w1, const float* __restrict__ b1,
    const float* __restrict__ w2, const float* __restrict__ b2,
    double* __restrict__ wd) {
  int t = blockIdx.x * 256 + threadIdx.x;
  if (t < 1176) wd[t] = (double)w1[t];
  else if (t < 1184) wd[t] = (double)b1[t - 1176];
  else if (t < 3184) wd[t] = (double)w2[t - 1184];
  else if (t < 3194) wd[t] = (double)b2[t - 3184];
}

// conv1 + relu + maxpool : in (64,224,224,3) f32 -> out (64,109,109,8) f64
// Half-batch launch: 32 batches starting at b0. Block: 4 pooled rows x
// 109 px (436 work items on 448 threads). Weights via scalar f64 loads.
__global__ __launch_bounds__(448) void k_conv1(
    const float* __restrict__ in, const double* __restrict__ wd,
    double* __restrict__ out, int b0) {
  __shared__ float win[14 * 672];   // 14 input rows x 224*3

  // XCD swizzle: 28 tiles/batch, 4 batches/group (group pinned to one XCD).
  int g = blockIdx.x & 7;
  int i = blockIdx.x >> 3;          // 0..111
  int b = b0 + g * 4 + i / 28;
  int tile = i % 28;
  int py0 = 4 * tile;               // first pooled row (last tile: 108 only)
  int r0 = 8 * tile;                // first input row of the 14-row band

  // stage 14 input rows (row clamped to 223), full width, as float4
  {
    const float* ibb = in + (size_t)b * 150528;
    for (int idx = threadIdx.x; idx < 14 * 168; idx += 448) {
      int rr = idx / 168, c4 = idx % 168;
      int row = min(r0 + rr, 223);
      float4 v = reinterpret_cast<const float4*>(ibb + (size_t)row * 672)[c4];
      reinterpret_cast<float4*>(&win[rr * 672])[c4] = v;
    }
  }
  __syncthreads();

  int t = threadIdx.x;
  int py = py0 + t / 109;
  if (t < 436 && py < 109) {
    int px = t % 109;
    int lrb = 2 * (t / 109);        // 0,2,4,6

    double acc[2][2][8];
#pragma unroll
    for (int ii = 0; ii < 2; ++ii)
#pragma unroll
      for (int j = 0; j < 2; ++j)
#pragma unroll
        for (int k = 0; k < 8; ++k) acc[ii][j][k] = 0.0;

    for (int ky = 0; ky < 7; ++ky) {
      const float* r0p = &win[(lrb + ky) * 672 + 6 * px];
      const float* r1p = r0p + 672;
      float a0[24], a1[24];
#pragma unroll
      for (int j = 0; j < 12; ++j) {
        float2 u = reinterpret_cast<const float2*>(r0p)[j];
        a0[2 * j] = u.x; a0[2 * j + 1] = u.y;
        float2 v = reinterpret_cast<const float2*>(r1p)[j];
        a1[2 * j] = v.x; a1[2 * j + 1] = v.y;
      }
      const double* wk = wd + ky * 168;   // 7 kx * 3 c * 8 oc per ky
#pragma unroll
      for (int kx = 0; kx < 7; ++kx) {
#pragma unroll
        for (int c = 0; c < 3; ++c) {
          double v00 = (double)a0[kx * 3 + c];
          double v01 = (double)a0[kx * 3 + 3 + c];
          double v10 = (double)a1[kx * 3 + c];
          double v11 = (double)a1[kx * 3 + 3 + c];
          const double* wp = wk + (kx * 3 + c) * 8;   // wave-uniform -> s_load
#pragma unroll
          for (int oc = 0; oc < 8; ++oc) {
            double wv = wp[oc];
            acc[0][0][oc] = fma(v00, wv, acc[0][0][oc]);
            acc[0][1][oc] = fma(v01, wv, acc[0][1][oc]);
            acc[1][0][oc] = fma(v10, wv, acc[1][0][oc]);
            acc[1][1][oc] = fma(v11, wv, acc[1][1][oc]);
          }
        }
      }
    }

    double* op = out + ((size_t)b * 11881 + (size_t)py * 109 + px) * 8;
#pragma unroll
    for (int oc = 0; oc < 8; ++oc) {
      double m = fmax(fmax(acc[0][0][oc], acc[0][1][oc]),
                      fmax(acc[1][0][oc], acc[1][1][oc]));
      op[oc] = fmax(m + wd[1176 + oc], 0.0);
    }
  }
}

// conv2 + relu + maxpool : in (64,109,109,8) f64 -> out (64,52,52,10) f64
// Block 512 = 2 oc-halves (wave-uniform, t>>8) x 256 (208 px-positions used).
// Parity-split planar band win2[cc][rr][par][56]; two channel-half passes.
// wd2: f64 conv2 weights, native ((ky*5+kx)*8+c)*10+oc layout; bias at 2000.
__global__ __launch_bounds__(512) void k_conv2(
    const double* __restrict__ in, const double* __restrict__ wd2,
    double* __restrict__ out) {
  __shared__ double win2[4 * 12 * 2 * 56];  // [cc][rr][par][k] = 43008 B

  // XCD swizzle: 13 tiles/batch (52/4 exact), 8 batches/group.
  int g = blockIdx.x & 7;
  int i = blockIdx.x >> 3;          // 0..103
  int b = g * 8 + i / 13;
  int tile = i % 13;
  int py0 = 4 * tile;
  int r0 = 8 * tile;                // 12-row band, max row 107 <= 108

  int t = threadIdx.x;
  // oh is uniform within each 64-lane wave (waves 0-3 -> 0, waves 4-7 -> 1);
  // readfirstlane forces the compiler to treat it as scalar so the weight
  // address computes in SGPRs -> s_load.
  int oh = __builtin_amdgcn_readfirstlane(t >> 8);
  int p = t & 255;                  // 0..255; 208 used
  bool valid = p < 208;
  int px = p % 52;
  int lrb = 2 * (p / 52);           // 0,2,4,6

  const double* wb = wd2 + oh * 5;  // scalar base for this oc-half

  double acc[2][2][5];
#pragma unroll
  for (int ii = 0; ii < 2; ++ii)
#pragma unroll
    for (int jj = 0; jj < 2; ++jj)
#pragma unroll
      for (int k = 0; k < 5; ++k) acc[ii][jj][k] = 0.0;

  const double* ib = in + (size_t)b * 11881 * 8;

  for (int h = 0; h < 2; ++h) {
    __syncthreads();  // protects win2 reuse across passes
    // stage 12 rows x 109 x channels [h*4..h*4+3], parity-split on x
    for (int idx = threadIdx.x; idx < 12 * 109 * 2; idx += 512) {
      int d2 = idx & 1;               // channel pair (0-1 / 2-3)
      int x  = (idx >> 1) % 109;
      int rr = (idx >> 1) / 109;
      double2 v = *reinterpret_cast<const double2*>(
          ib + ((size_t)(r0 + rr) * 109 + x) * 8 + h * 4 + d2 * 2);
      int par = x & 1, k = x >> 1;
      win2[(((d2 * 2) * 12 + rr) * 2 + par) * 56 + k] = v.x;
      win2[(((d2 * 2 + 1) * 12 + rr) * 2 + par) * 56 + k] = v.y;
    }
    __syncthreads();

    if (valid) {
#pragma unroll
      for (int ky = 0; ky < 5; ++ky) {
        int rr0 = lrb + ky;
#pragma unroll
        for (int cc = 0; cc < 4; ++cc) {
          int c = h * 4 + cc;
          // hoist the 12 window doubles for this (ky,cc): rows rr0,rr0+1,
          // both parities, k = px..px+2.  x = 2px+j -> par=j&1, k=px+(j>>1).
          const double* pe0 = &win2[((cc * 12 + rr0) * 2 + 0) * 56 + px];
          const double* po0 = &win2[((cc * 12 + rr0) * 2 + 1) * 56 + px];
          const double* pe1 = pe0 + 112;   // rr0+1
          const double* po1 = po0 + 112;
          double e0[3] = {pe0[0], pe0[1], pe0[2]};
          double o0[3] = {po0[0], po0[1], po0[2]};
          double e1[3] = {pe1[0], pe1[1], pe1[2]};
          double o1[3] = {po1[0], po1[1], po1[2]};
#pragma unroll
          for (int kx = 0; kx < 5; ++kx) {
            double v00, v01, v10, v11;
            if (kx & 1) {
              v00 = o0[kx >> 1]; v01 = e0[(kx >> 1) + 1];
              v10 = o1[kx >> 1]; v11 = e1[(kx >> 1) + 1];
            } else {
              v00 = e0[kx >> 1]; v01 = o0[kx >> 1];
              v10 = e1[kx >> 1]; v11 = o1[kx >> 1];
            }
            const double* wp = wb + ((ky * 5 + kx) * 8 + c) * 10;  // scalar
#pragma unroll
            for (int oc = 0; oc < 5; ++oc) {
              double wv = wp[oc];
              acc[0][0][oc] = fma(v00, wv, acc[0][0][oc]);
              acc[0][1][oc] = fma(v01, wv, acc[0][1][oc]);
              acc[1][0][oc] = fma(v10, wv, acc[1][0][oc]);
              acc[1][1][oc] = fma(v11, wv, acc[1][1][oc]);
            }
          }
        }
      }
    }
  }

  if (valid) {
    int pix = py0 * 52 + p;           // p row-major within tile
    double* op = out + ((size_t)b * 2704 + pix) * 10 + oh * 5;
#pragma unroll
    for (int oc = 0; oc < 5; ++oc) {
      double m = fmax(fmax(acc[0][0][oc], acc[0][1][oc]),
                      fmax(acc[1][0][oc], acc[1][1][oc]));
      op[oc] = fmax(m + wd2[2000 + oh * 5 + oc], 0.0);
    }
  }
}

// fc1 partial dots: grid 1024 = (64 b) x (16 q); block 256 = 32 oc x 8 strips.
__global__ __launch_bounds__(256) void k_fc1(
    const double* __restrict__ xs, const float* __restrict__ w1,
    double* __restrict__ part) {
  int b = blockIdx.x >> 4;
  int q = blockIdx.x & 15;
  int oc = threadIdx.x & 31;
  int s = threadIdx.x >> 5;
  const double* xrow = xs + (size_t)b * 27040;

  int i0 = q * 1690 + s * 212;
  int i1 = min(i0 + 212, q * 1690 + 1690);
  double s0 = 0.0, s1 = 0.0;
  for (int i = i0; i + 1 < i1; i += 2) {
    s0 = fma(xrow[i],     (double)w1[(size_t)i * 32 + oc],       s0);
    s1 = fma(xrow[i + 1], (double)w1[(size_t)(i + 1) * 32 + oc], s1);
  }
  if ((i1 - i0) & 1)
    s0 = fma(xrow[i1 - 1], (double)w1[(size_t)(i1 - 1) * 32 + oc], s0);

  __shared__ double red[8][32];
  red[s][oc] = s0 + s1;
  __syncthreads();
  if (threadIdx.x < 32) {
    double v = 0.0;
#pragma unroll
    for (int k = 0; k < 8; ++k) v += red[k][threadIdx.x];
    part[((size_t)b * 16 + q) * 32 + threadIdx.x] = v;
  }
}

// fc1 reduce + ReLU + fc2 -> theta. 64 blocks x 64 threads.
__global__ __launch_bounds__(64) void k_fc2(
    const double* __restrict__ part, const float* __restrict__ b1,
    const float* __restrict__ w2, const float* __restrict__ b2,
    double* __restrict__ theta) {
  int b = blockIdx.x;
  __shared__ double h1[32];
  if (threadIdx.x < 32) {
    double v = (double)b1[threadIdx.x];
#pragma unroll
    for (int q = 0; q < 16; ++q)
      v += part[((size_t)b * 16 + q) * 32 + threadIdx.x];
    h1[threadIdx.x] = v > 0.0 ? v : 0.0;
  }
  __syncthreads();
  if (threadIdx.x < 6) {
    double v = (double)b2[threadIdx.x];
#pragma unroll
    for (int k = 0; k < 32; ++k) v += h1[k] * (double)w2[k * 6 + threadIdx.x];
    theta[b * 6 + threadIdx.x] = v;
  }
}

// affine grid + bilinear sampler, reference-exact (incl. extrapolation quirk).
__global__ __launch_bounds__(256) void k_sample(
    const float* __restrict__ img, const double* __restrict__ theta,
    float* __restrict__ out) {
  int idx = blockIdx.x * 256 + threadIdx.x;
  if (idx >= 64 * 224 * 224) return;
  int x = idx % 224;
  int t = idx / 224;
  int y = t % 224;
  int b = t / 224;

  const double* th = theta + b * 6;
  double t0 = th[0], t1 = th[1], t2 = th[2];
  double t3 = th[3], t4 = th[4], t5 = th[5];

  double xn = -1.0 + x * (2.0 / 223.0);
  double yn = -1.0 + y * (2.0 / 223.0);
  double xf = 0.5 * (t0 * xn + t1 * yn + t2 + 1.0) * 223.0;
  double yf = 0.5 * (t3 * xn + t4 * yn + t5 + 1.0) * 223.0;

  int x0 = (int)floor(xf);
  int y0 = (int)floor(yf);
  x0 = min(max(x0, 0), 223);
  y0 = min(max(y0, 0), 223);
  int x1 = min(x0 + 1, 223);
  int y1 = min(y0 + 1, 223);

  double x0f = (double)x0, x1f = (double)x1;
  double y0f = (double)y0, y1f = (double)y1;
  // weights from UNCLIPPED xf/yf — reference semantics (extrapolates)
  double wa = (x1f - xf) * (y1f - yf);
  double wb = (x1f - xf) * (yf - y0f);
  double wc = (xf - x0f) * (y1f - yf);
  double wd = (xf - x0f) * (yf - y0f);

  const float* p = img + (size_t)b * 150528;
  const float* Ia = p + ((size_t)y0 * 224 + x0) * 3;
  const float* Ib = p + ((size_t)y1 * 224 + x0) * 3;
  const float* Ic = p + ((size_t)y0 * 224 + x1) * 3;
  const float* Id = p + ((size_t)y1 * 224 + x1) * 3;

  float* op = out + (size_t)idx * 3;
#pragma unroll
  for (int c = 0; c < 3; ++c) {
    op[c] = (float)(wa * (double)Ia[c] + wb * (double)Ib[c] +
                    wc * (double)Ic[c] + wd * (double)Id[c]);
  }
}

extern "C" void kernel_launch(void* const* d_in, const int* in_sizes, int n_in,
                              void* d_out, int out_size, void* d_ws, size_t ws_size,
                              hipStream_t stream) {
  const float* inputs  = (const float*)d_in[0];  // (64,224,224,3)
  const float* conv1_w = (const float*)d_in[1];  // (7,7,3,8)
  const float* conv1_b = (const float*)d_in[2];  // (8)
  const float* conv2_w = (const float*)d_in[3];  // (5,5,8,10)
  const float* conv2_b = (const float*)d_in[4];  // (10)
  const float* fc1_w   = (const float*)d_in[5];  // (27040,32)
  const float* fc1_b   = (const float*)d_in[6];  // (32)
  const float* fc2_w   = (const float*)d_in[7];  // (32,6)
  const float* fc2_b   = (const float*)d_in[8];  // (6)
  float* outp = (float*)d_out;                   // (64,224,224,3)

  // ws layout (16B aligned): theta | fc partials | f64 weights | pools
  double* theta = (double*)d_ws;                            // 384 dbl
  double* part  = (double*)((char*)d_ws + 4096);            // 32768 dbl
  double* wd    = (double*)((char*)d_ws + 4096 + 262144);   // 3194 dbl -> pad 3200 (25600B)
  double* pool1 = (double*)((char*)d_ws + 4096 + 262144 + 25600); // 6,083,072 d
  double* pool2 = pool1 + 6083072;                          // 1,730,560 d

  // Stage 0: f64 weight conversion (conv1 + conv2) for scalar-load path
  k_wcvt<<<13, 256, 0, stream>>>(conv1_w, conv1_b, conv2_w, conv2_b, wd);
  // Stage 1: two half-batch launches (attribution: each ~83us so the true
  // #2 kernel surfaces in rocprof top-5). 28 tiles x 32 batches each.
  k_conv1<<<28 * 32, 448, 0, stream>>>(inputs, wd, pool1, 0);
  k_conv1<<<28 * 32, 448, 0, stream>>>(inputs, wd, pool1, 32);
  // Stage 2: 13 tiles/batch * 64 batches (512-thread blocks), XCD-grouped
  k_conv2<<<13 * 64, 512, 0, stream>>>(pool1, wd + 1184, pool2);
  // Stage 3
  k_fc1<<<1024, 256, 0, stream>>>(pool2, fc1_w, part);
  k_fc2<<<64, 64, 0, stream>>>(part, fc1_b, fc2_w, fc2_b, theta);
  // Stage 4
  k_sample<<<(64 * 224 * 224 + 255) / 256, 256, 0, stream>>>(inputs, theta, outp);
}

// Round 8
// 395.214 us; speedup vs baseline: 1.1546x; 1.0899x over previous
//
#include <hip/hip_runtime.h>

// ---------------------------------------------------------------------------
// STN pipeline, theta chain in FP64 (must match np float64 reference: sampler
// has floor() discontinuities at coord==223 with O(100..1000) jumps; f32
// noise upstream of theta flips floors -> fails. Any-order f64 lands ~1e-13
// from the np value -> flip set identical -> absmax small & stable).
//
// R16: conv2 PARALLELISM round. R15 attribution: conv2=111.5us, VALUBusy 42%
// (issue near-floor: 17.3K cyc/wave vs 16K FMA), idle 58%, conflicts 1.98M,
// grid only 3.25 blocks/CU. Empirical law across R9-R15: blocks/CU 7->72%
// busy, 3.25->42%, 1->51%. Fix: halve tile to 2 pooled rows -> 1664 blocks
// (6.5/CU) x 256 thr; same per-thread math (bit-identical f64 per output).
// Pad LDS plane 56->57 (row stride 228 words = bank+4, breaks the aligned
// congruence behind the 1.98M conflict cycles).
// conv1 reverted to proven R10 single launch (R15 split cost ~37us).
// R12-R14 conv1 restructures all REFUTED; R10 scalar weights 181->164us.
// ---------------------------------------------------------------------------

// Convert conv1 w+b and conv2 w+b to f64 once per graph execution.
// wd layout: [0,1176) conv1_w | [1176,1184) conv1_b
//            [1184,3184) conv2_w (native (ky,kx,c,oc) order) | [3184,3194) conv2_b
__global__ __launch_bounds__(256) void k_wcvt(
    const float* __restrict__ w1, const float* __restrict__ b1,
    const float* __restrict__ w2, const float* __restrict__ b2,
    double* __restrict__ wd) {
  int t = blockIdx.x * 256 + threadIdx.x;
  if (t < 1176) wd[t] = (double)w1[t];
  else if (t < 1184) wd[t] = (double)b1[t - 1176];
  else if (t < 3184) wd[t] = (double)w2[t - 1184];
  else if (t < 3194) wd[t] = (double)b2[t - 3184];
}

// conv1 + relu + maxpool : in (64,224,224,3) f32 -> out (64,109,109,8) f64
// Block: 4 pooled rows x 109 px (436 work items on 448 threads).
// Weights/bias come from global f64 (wd), read via scalar loads (uniform).
__global__ __launch_bounds__(448) void k_conv1(
    const float* __restrict__ in, const double* __restrict__ wd,
    double* __restrict__ out) {
  __shared__ float win[14 * 672];   // 14 input rows x 224*3

  // XCD swizzle: 28 tiles/batch, 8 batches/group (group pinned to one XCD).
  int g = blockIdx.x & 7;
  int i = blockIdx.x >> 3;          // 0..223
  int b = g * 8 + i / 28;
  int tile = i % 28;
  int py0 = 4 * tile;               // first pooled row (last tile: 108 only)
  int r0 = 8 * tile;                // first input row of the 14-row band

  // stage 14 input rows (row clamped to 223), full width, as float4
  {
    const float* ibb = in + (size_t)b * 150528;
    for (int idx = threadIdx.x; idx < 14 * 168; idx += 448) {
      int rr = idx / 168, c4 = idx % 168;
      int row = min(r0 + rr, 223);
      float4 v = reinterpret_cast<const float4*>(ibb + (size_t)row * 672)[c4];
      reinterpret_cast<float4*>(&win[rr * 672])[c4] = v;
    }
  }
  __syncthreads();

  int t = threadIdx.x;
  int py = py0 + t / 109;
  if (t < 436 && py < 109) {
    int px = t % 109;
    int lrb = 2 * (t / 109);        // 0,2,4,6

    double acc[2][2][8];
#pragma unroll
    for (int ii = 0; ii < 2; ++ii)
#pragma unroll
      for (int j = 0; j < 2; ++j)
#pragma unroll
        for (int k = 0; k < 8; ++k) acc[ii][j][k] = 0.0;

    for (int ky = 0; ky < 7; ++ky) {
      const float* r0p = &win[(lrb + ky) * 672 + 6 * px];
      const float* r1p = r0p + 672;
      float a0[24], a1[24];
#pragma unroll
      for (int j = 0; j < 12; ++j) {
        float2 u = reinterpret_cast<const float2*>(r0p)[j];
        a0[2 * j] = u.x; a0[2 * j + 1] = u.y;
        float2 v = reinterpret_cast<const float2*>(r1p)[j];
        a1[2 * j] = v.x; a1[2 * j + 1] = v.y;
      }
      const double* wk = wd + ky * 168;   // 7 kx * 3 c * 8 oc per ky
#pragma unroll
      for (int kx = 0; kx < 7; ++kx) {
#pragma unroll
        for (int c = 0; c < 3; ++c) {
          double v00 = (double)a0[kx * 3 + c];
          double v01 = (double)a0[kx * 3 + 3 + c];
          double v10 = (double)a1[kx * 3 + c];
          double v11 = (double)a1[kx * 3 + 3 + c];
          const double* wp = wk + (kx * 3 + c) * 8;   // wave-uniform -> s_load
#pragma unroll
          for (int oc = 0; oc < 8; ++oc) {
            double wv = wp[oc];
            acc[0][0][oc] = fma(v00, wv, acc[0][0][oc]);
            acc[0][1][oc] = fma(v01, wv, acc[0][1][oc]);
            acc[1][0][oc] = fma(v10, wv, acc[1][0][oc]);
            acc[1][1][oc] = fma(v11, wv, acc[1][1][oc]);
          }
        }
      }
    }

    double* op = out + ((size_t)b * 11881 + (size_t)py * 109 + px) * 8;
#pragma unroll
    for (int oc = 0; oc < 8; ++oc) {
      double m = fmax(fmax(acc[0][0][oc], acc[0][1][oc]),
                      fmax(acc[1][0][oc], acc[1][1][oc]));
      op[oc] = fmax(m + wd[1176 + oc], 0.0);
    }
  }
}

// conv2 + relu + maxpool : in (64,109,109,8) f64 -> out (64,52,52,10) f64
// Small-tile: 2 pooled rows/block, 26 tiles/batch -> 1664 blocks (6.5/CU).
// Block 256 = 2 oc-halves (wave-uniform, t>>7) x 128 (104 used).
// Parity-split planar band win2[cc][rr][par][57] (pad 57 breaks bank
// congruence: row stride 228 words = bank+4). Two channel-half passes.
// wd2: f64 conv2 weights, native ((ky*5+kx)*8+c)*10+oc layout; bias at 2000.
__global__ __launch_bounds__(256) void k_conv2(
    const double* __restrict__ in, const double* __restrict__ wd2,
    double* __restrict__ out) {
  __shared__ double win2[4 * 8 * 2 * 57];  // [cc][rr][par][k] = 29184 B

  // XCD swizzle: 26 tiles/batch, 8 batches/group.
  int g = blockIdx.x & 7;
  int i = blockIdx.x >> 3;          // 0..207
  int b = g * 8 + i / 26;
  int tile = i % 26;
  int py0 = 2 * tile;               // pooled rows py0, py0+1
  int r0 = 4 * tile;                // 8-row band, max row 4*25+7 = 107 <= 108

  int t = threadIdx.x;
  // oh uniform per wave (waves 0-1 -> 0, waves 2-3 -> 1); readfirstlane
  // forces the scalar path so weight addresses compute in SGPRs -> s_load.
  int oh = __builtin_amdgcn_readfirstlane(t >> 7);
  int p = t & 127;                  // 0..127; 104 used
  bool valid = p < 104;
  int px = p % 52;
  int lrb = 2 * (p / 52);           // 0,2

  const double* wb = wd2 + oh * 5;  // scalar base for this oc-half

  double acc[2][2][5];
#pragma unroll
  for (int ii = 0; ii < 2; ++ii)
#pragma unroll
    for (int jj = 0; jj < 2; ++jj)
#pragma unroll
      for (int k = 0; k < 5; ++k) acc[ii][jj][k] = 0.0;

  const double* ib = in + (size_t)b * 11881 * 8;

  for (int h = 0; h < 2; ++h) {
    __syncthreads();  // protects win2 reuse across passes
    // stage 8 rows x 109 x channels [h*4..h*4+3], parity-split on x
    for (int idx = threadIdx.x; idx < 8 * 109 * 2; idx += 256) {
      int d2 = idx & 1;               // channel pair (0-1 / 2-3)
      int x  = (idx >> 1) % 109;
      int rr = (idx >> 1) / 109;
      double2 v = *reinterpret_cast<const double2*>(
          ib + ((size_t)(r0 + rr) * 109 + x) * 8 + h * 4 + d2 * 2);
      int par = x & 1, k = x >> 1;
      win2[(((d2 * 2) * 8 + rr) * 2 + par) * 57 + k] = v.x;
      win2[(((d2 * 2 + 1) * 8 + rr) * 2 + par) * 57 + k] = v.y;
    }
    __syncthreads();

    if (valid) {
#pragma unroll
      for (int ky = 0; ky < 5; ++ky) {
        int rr0 = lrb + ky;
#pragma unroll
        for (int cc = 0; cc < 4; ++cc) {
          int c = h * 4 + cc;
          // hoist the 12 window doubles for this (ky,cc): rows rr0,rr0+1,
          // both parities, k = px..px+2.  x = 2px+j -> par=j&1, k=px+(j>>1).
          const double* pe0 = &win2[((cc * 8 + rr0) * 2 + 0) * 57 + px];
          const double* po0 = pe0 + 57;    // par 1
          const double* pe1 = pe0 + 114;   // rr0+1, par 0
          const double* po1 = pe0 + 171;   // rr0+1, par 1
          double e0[3] = {pe0[0], pe0[1], pe0[2]};
          double o0[3] = {po0[0], po0[1], po0[2]};
          double e1[3] = {pe1[0], pe1[1], pe1[2]};
          double o1[3] = {po1[0], po1[1], po1[2]};
#pragma unroll
          for (int kx = 0; kx < 5; ++kx) {
            double v00, v01, v10, v11;
            if (kx & 1) {
              v00 = o0[kx >> 1]; v01 = e0[(kx >> 1) + 1];
              v10 = o1[kx >> 1]; v11 = e1[(kx >> 1) + 1];
            } else {
              v00 = e0[kx >> 1]; v01 = o0[kx >> 1];
              v10 = e1[kx >> 1]; v11 = o1[kx >> 1];
            }
            const double* wp = wb + ((ky * 5 + kx) * 8 + c) * 10;  // scalar
#pragma unroll
            for (int oc = 0; oc < 5; ++oc) {
              double wv = wp[oc];
              acc[0][0][oc] = fma(v00, wv, acc[0][0][oc]);
              acc[0][1][oc] = fma(v01, wv, acc[0][1][oc]);
              acc[1][0][oc] = fma(v10, wv, acc[1][0][oc]);
              acc[1][1][oc] = fma(v11, wv, acc[1][1][oc]);
            }
          }
        }
      }
    }
  }

  if (valid) {
    int pix = py0 * 52 + p;           // p row-major within tile (2 rows x 52)
    double* op = out + ((size_t)b * 2704 + pix) * 10 + oh * 5;
#pragma unroll
    for (int oc = 0; oc < 5; ++oc) {
      double m = fmax(fmax(acc[0][0][oc], acc[0][1][oc]),
                      fmax(acc[1][0][oc], acc[1][1][oc]));
      op[oc] = fmax(m + wd2[2000 + oh * 5 + oc], 0.0);
    }
  }
}

// fc1 partial dots: grid 1024 = (64 b) x (16 q); block 256 = 32 oc x 8 strips.
__global__ __launch_bounds__(256) void k_fc1(
    const double* __restrict__ xs, const float* __restrict__ w1,
    double* __restrict__ part) {
  int b = blockIdx.x >> 4;
  int q = blockIdx.x & 15;
  int oc = threadIdx.x & 31;
  int s = threadIdx.x >> 5;
  const double* xrow = xs + (size_t)b * 27040;

  int i0 = q * 1690 + s * 212;
  int i1 = min(i0 + 212, q * 1690 + 1690);
  double s0 = 0.0, s1 = 0.0;
  for (int i = i0; i + 1 < i1; i += 2) {
    s0 = fma(xrow[i],     (double)w1[(size_t)i * 32 + oc],       s0);
    s1 = fma(xrow[i + 1], (double)w1[(size_t)(i + 1) * 32 + oc], s1);
  }
  if ((i1 - i0) & 1)
    s0 = fma(xrow[i1 - 1], (double)w1[(size_t)(i1 - 1) * 32 + oc], s0);

  __shared__ double red[8][32];
  red[s][oc] = s0 + s1;
  __syncthreads();
  if (threadIdx.x < 32) {
    double v = 0.0;
#pragma unroll
    for (int k = 0; k < 8; ++k) v += red[k][threadIdx.x];
    part[((size_t)b * 16 + q) * 32 + threadIdx.x] = v;
  }
}

// fc1 reduce + ReLU + fc2 -> theta. 64 blocks x 64 threads.
__global__ __launch_bounds__(64) void k_fc2(
    const double* __restrict__ part, const float* __restrict__ b1,
    const float* __restrict__ w2, const float* __restrict__ b2,
    double* __restrict__ theta) {
  int b = blockIdx.x;
  __shared__ double h1[32];
  if (threadIdx.x < 32) {
    double v = (double)b1[threadIdx.x];
#pragma unroll
    for (int q = 0; q < 16; ++q)
      v += part[((size_t)b * 16 + q) * 32 + threadIdx.x];
    h1[threadIdx.x] = v > 0.0 ? v : 0.0;
  }
  __syncthreads();
  if (threadIdx.x < 6) {
    double v = (double)b2[threadIdx.x];
#pragma unroll
    for (int k = 0; k < 32; ++k) v += h1[k] * (double)w2[k * 6 + threadIdx.x];
    theta[b * 6 + threadIdx.x] = v;
  }
}

// affine grid + bilinear sampler, reference-exact (incl. extrapolation quirk).
__global__ __launch_bounds__(256) void k_sample(
    const float* __restrict__ img, const double* __restrict__ theta,
    float* __restrict__ out) {
  int idx = blockIdx.x * 256 + threadIdx.x;
  if (idx >= 64 * 224 * 224) return;
  int x = idx % 224;
  int t = idx / 224;
  int y = t % 224;
  int b = t / 224;

  const double* th = theta + b * 6;
  double t0 = th[0], t1 = th[1], t2 = th[2];
  double t3 = th[3], t4 = th[4], t5 = th[5];

  double xn = -1.0 + x * (2.0 / 223.0);
  double yn = -1.0 + y * (2.0 / 223.0);
  double xf = 0.5 * (t0 * xn + t1 * yn + t2 + 1.0) * 223.0;
  double yf = 0.5 * (t3 * xn + t4 * yn + t5 + 1.0) * 223.0;

  int x0 = (int)floor(xf);
  int y0 = (int)floor(yf);
  x0 = min(max(x0, 0), 223);
  y0 = min(max(y0, 0), 223);
  int x1 = min(x0 + 1, 223);
  int y1 = min(y0 + 1, 223);

  double x0f = (double)x0, x1f = (double)x1;
  double y0f = (double)y0, y1f = (double)y1;
  // weights from UNCLIPPED xf/yf — reference semantics (extrapolates)
  double wa = (x1f - xf) * (y1f - yf);
  double wb = (x1f - xf) * (yf - y0f);
  double wc = (xf - x0f) * (y1f - yf);
  double wd = (xf - x0f) * (yf - y0f);

  const float* p = img + (size_t)b * 150528;
  const float* Ia = p + ((size_t)y0 * 224 + x0) * 3;
  const float* Ib = p + ((size_t)y1 * 224 + x0) * 3;
  const float* Ic = p + ((size_t)y0 * 224 + x1) * 3;
  const float* Id = p + ((size_t)y1 * 224 + x1) * 3;

  float* op = out + (size_t)idx * 3;
#pragma unroll
  for (int c = 0; c < 3; ++c) {
    op[c] = (float)(wa * (double)Ia[c] + wb * (double)Ib[c] +
                    wc * (double)Ic[c] + wd * (double)Id[c]);
  }
}

extern "C" void kernel_launch(void* const* d_in, const int* in_sizes, int n_in,
                              void* d_out, int out_size, void* d_ws, size_t ws_size,
                              hipStream_t stream) {
  const float* inputs  = (const float*)d_in[0];  // (64,224,224,3)
  const float* conv1_w = (const float*)d_in[1];  // (7,7,3,8)
  const float* conv1_b = (const float*)d_in[2];  // (8)
  const float* conv2_w = (const float*)d_in[3];  // (5,5,8,10)
  const float* conv2_b = (const float*)d_in[4];  // (10)
  const float* fc1_w   = (const float*)d_in[5];  // (27040,32)
  const float* fc1_b   = (const float*)d_in[6];  // (32)
  const float* fc2_w   = (const float*)d_in[7];  // (32,6)
  const float* fc2_b   = (const float*)d_in[8];  // (6)
  float* outp = (float*)d_out;                   // (64,224,224,3)

  // ws layout (16B aligned): theta | fc partials | f64 weights | pools
  double* theta = (double*)d_ws;                            // 384 dbl
  double* part  = (double*)((char*)d_ws + 4096);            // 32768 dbl
  double* wd    = (double*)((char*)d_ws + 4096 + 262144);   // 3194 dbl -> pad 3200 (25600B)
  double* pool1 = (double*)((char*)d_ws + 4096 + 262144 + 25600); // 6,083,072 d
  double* pool2 = pool1 + 6083072;                          // 1,730,560 d

  // Stage 0: f64 weight conversion (conv1 + conv2) for scalar-load path
  k_wcvt<<<13, 256, 0, stream>>>(conv1_w, conv1_b, conv2_w, conv2_b, wd);
  // Stage 1: 28 tiles/batch * 64 batches (448-thread blocks), XCD-grouped
  k_conv1<<<28 * 64, 448, 0, stream>>>(inputs, wd, pool1);
  // Stage 2: 26 small tiles/batch * 64 batches (256-thread blocks, 6.5/CU)
  k_conv2<<<26 * 64, 256, 0, stream>>>(pool1, wd + 1184, pool2);
  // Stage 3
  k_fc1<<<1024, 256, 0, stream>>>(pool2, fc1_w, part);
  k_fc2<<<64, 64, 0, stream>>>(part, fc1_b, fc2_w, fc2_b, theta);
  // Stage 4
  k_sample<<<(64 * 224 * 224 + 255) / 256, 256, 0, stream>>>(inputs, theta, outp);
}